// Round 6
// baseline (207.770 us; speedup 1.0000x reference)
//
#include <hip/hip_runtime.h>
#include <hip/hip_bf16.h>

typedef __bf16 bf16x8 __attribute__((ext_vector_type(8)));
typedef __bf16 bf16x4 __attribute__((ext_vector_type(4)));
typedef float  f32x4  __attribute__((ext_vector_type(4)));

#define NB 4
#define SEQ 4096
#define DIM 128

static __device__ __forceinline__ unsigned int bf16bits(__bf16 h) {
    return (unsigned int)__builtin_bit_cast(unsigned short, h);
}

// ---------------------------------------------------------------------------
// Kernel 0: W fp32 -> (Wh, Wl) bf16 split pair.  Wh = bf16(w), Wl = bf16(w-Wh)
// ---------------------------------------------------------------------------
__global__ __launch_bounds__(256) void wconv(
    const float* __restrict__ Wq, const float* __restrict__ Wk,
    const float* __restrict__ Wv,
    __bf16* __restrict__ Wh, __bf16* __restrict__ Wl)
{
    int idx = blockIdx.x * 256 + threadIdx.x;     // float4 index, 12288 total
    int which = idx >> 12;                        // 4096 float4 per matrix
    int off = (idx & 4095) * 4;
    const float* W = which == 0 ? Wq : (which == 1 ? Wk : Wv);
    float4 v = *(const float4*)(W + off);
    bf16x4 h, lo;
    h[0] = (__bf16)v.x; h[1] = (__bf16)v.y; h[2] = (__bf16)v.z; h[3] = (__bf16)v.w;
    lo[0] = (__bf16)(v.x - (float)h[0]);
    lo[1] = (__bf16)(v.y - (float)h[1]);
    lo[2] = (__bf16)(v.z - (float)h[2]);
    lo[3] = (__bf16)(v.w - (float)h[3]);
    *(bf16x4*)(Wh + which * 16384 + off) = h;
    *(bf16x4*)(Wl + which * 16384 + off) = lo;
}

// ---------------------------------------------------------------------------
// Kernel 1: QKV projection via 3-term split-bf16 MFMA (fp32-grade accuracy).
// (unchanged from R4 — passed; ~28 µs, revisit later if attn drops below it)
// ---------------------------------------------------------------------------
__global__ __launch_bounds__(256) void qkv_proj(
    const float* __restrict__ x,
    const __bf16* __restrict__ Whg, const __bf16* __restrict__ Wlg,
    const float* __restrict__ bq, const float* __restrict__ bk,
    const float* __restrict__ bv,
    __bf16* __restrict__ Q, __bf16* __restrict__ K, __bf16* __restrict__ Vt)
{
    __shared__ __bf16 vbuf[64][136];
    const int t  = threadIdx.x;
    const int w  = t >> 6, l = t & 63, lg = l >> 4, ll = l & 15;
    const int rt = blockIdx.x, which = blockIdx.y;

    const __bf16* Wh = Whg + which * 16384;
    const __bf16* Wl = Wlg + which * 16384;
    const float* bias = which == 0 ? bq : (which == 1 ? bk : bv);

    float bfr[8];
    #pragma unroll
    for (int ct = 0; ct < 8; ++ct) bfr[ct] = bias[ct * 16 + ll];

    f32x4 acc[8];
    #pragma unroll
    for (int ct = 0; ct < 8; ++ct) acc[ct] = (f32x4){0.f, 0.f, 0.f, 0.f};

    const float* xrow = x + (rt * 64 + w * 16 + ll) * 128;

    #pragma unroll 1
    for (int kb = 0; kb < 4; ++kb) {
        float4 xa = *(const float4*)(xrow + kb * 32 + lg * 8);
        float4 xb = *(const float4*)(xrow + kb * 32 + lg * 8 + 4);
        float xv[8] = {xa.x, xa.y, xa.z, xa.w, xb.x, xb.y, xb.z, xb.w};
        bf16x8 xh, xl;
        #pragma unroll
        for (int j = 0; j < 8; ++j) {
            __bf16 h = (__bf16)xv[j];
            xh[j] = h;
            xl[j] = (__bf16)(xv[j] - (float)h);
        }
        #pragma unroll
        for (int ct = 0; ct < 8; ++ct) {
            bf16x8 wh = *(const bf16x8*)(Wh + (ct * 16 + ll) * 128 + kb * 32 + lg * 8);
            bf16x8 wl = *(const bf16x8*)(Wl + (ct * 16 + ll) * 128 + kb * 32 + lg * 8);
            acc[ct] = __builtin_amdgcn_mfma_f32_16x16x32_bf16(xh, wh, acc[ct], 0, 0, 0);
            acc[ct] = __builtin_amdgcn_mfma_f32_16x16x32_bf16(xh, wl, acc[ct], 0, 0, 0);
            acc[ct] = __builtin_amdgcn_mfma_f32_16x16x32_bf16(xl, wh, acc[ct], 0, 0, 0);
        }
    }

    const float qscale = 0.08838834764831845f;  // 1/sqrt(128)
    const float scale = (which == 0) ? qscale : 1.0f;
    #pragma unroll
    for (int ct = 0; ct < 8; ++ct)
        #pragma unroll
        for (int r = 0; r < 4; ++r)
            vbuf[w * 16 + lg * 4 + r][ct * 16 + ll] = (__bf16)((acc[ct][r] + bfr[ct]) * scale);
    __syncthreads();

    if (which < 2) {
        __bf16* dst = (which == 0 ? Q : K) + (rt * 64 + (t >> 2)) * 128 + (t & 3) * 32;
        const __bf16* src = &vbuf[t >> 2][(t & 3) * 32];
        #pragma unroll
        for (int i = 0; i < 4; ++i) ((bf16x8*)dst)[i] = ((const bf16x8*)src)[i];
    } else {
        int e = t >> 1, sh = (t & 1) * 32;
        int bb = rt >> 6, sb = (rt & 63) * 64 + sh;
        __bf16 tmp[32];
        #pragma unroll
        for (int j = 0; j < 32; ++j) tmp[j] = vbuf[sh + j][e];
        __bf16* dst = Vt + bb * (128 * 4096) + e * 4096 + sb;
        #pragma unroll
        for (int i = 0; i < 4; ++i) ((bf16x8*)dst)[i] = *(const bf16x8*)&tmp[i * 8];
    }
}

// ---------------------------------------------------------------------------
// Kernel 2: flash attention. 256 blocks x 512 thr (8 waves = 2 k-groups x 4
// q-frags). Per-group DOUBLE-BUFFERED K/V LDS, ONE barrier per iteration,
// XOR-swizzled tiles (unit16 ^= row&7), defer-max online softmax (THR=8).
// Swapped QK^T: lane (ll,lg) reg(nt,r) = S[key=nt*16+lg*4+r][q=ll].
// ---------------------------------------------------------------------------
struct ShA {
    __bf16 Kl[2][2][64][128];    // [group][buf][key][d]  (swizzled units)
    __bf16 Vl[2][2][128][64];    // [group][buf][d][key]  (swizzled units)
    __bf16 PlT[8][16][72];       // per-wave P transpose, +8 pad
};
struct ShB {
    float Obuf[64][132];
    float m_l[2][64], l_l[2][64];
};
union ShU { ShA a; ShB b; };

__global__ __launch_bounds__(512, 2) void attn_fwd(
    const __bf16* __restrict__ Qg,
    const __bf16* __restrict__ Kg,
    const __bf16* __restrict__ Vt,
    float* __restrict__ out)
{
    __shared__ ShU sh;

    const int t  = threadIdx.x;
    const int w  = t >> 6;        // 0..7
    const int g  = w >> 2;        // split-K group
    const int wl = w & 3;         // q-frag within group
    const int l  = t & 63, lg = l >> 4, ll = l & 15;
    const int tg = t & 255;       // thread within group
    const int sK = ll & 7;        // read-side swizzle key

    const int bid = blockIdx.x;
    const int b = bid >> 6, qt = bid & 63;
    const int rb = wl * 16;
    const int qrow0 = qt * 64 + rb;

    bf16x8 qa[4];
    const __bf16* qbase = Qg + (b * 4096 + qrow0 + ll) * 128 + lg * 8;
    #pragma unroll
    for (int kb = 0; kb < 4; ++kb) qa[kb] = *(const bf16x8*)(qbase + kb * 32);

    f32x4 o[8];
    #pragma unroll
    for (int dt = 0; dt < 8; ++dt) o[dt] = (f32x4){0.f, 0.f, 0.f, 0.f};
    float m = -1e30f, lsum = 0.f;

    const __bf16* kbase = Kg + (long)(b * 4096 + g * 2048) * 128;
    const __bf16* vbase = Vt + (long)b * 128 * 4096 + g * 2048;

    // staging decomposition (per thread: 4 K units + 4 V units of 16B)
    int krow[4], kuc[4], kswz[4], vrow[4], vuc[4], vswz[4];
    #pragma unroll
    for (int ii = 0; ii < 4; ++ii) {
        int u = tg + ii * 256;
        krow[ii] = u >> 4; kuc[ii] = u & 15; kswz[ii] = kuc[ii] ^ (krow[ii] & 7);
        vrow[ii] = u >> 3; vuc[ii] = u & 7;  vswz[ii] = vuc[ii] ^ (vrow[ii] & 7);
    }

    bf16x8 kreg[4], vreg[4];
    // prologue: tile 0 -> buf 0
    #pragma unroll
    for (int ii = 0; ii < 4; ++ii)
        kreg[ii] = *(const bf16x8*)(kbase + krow[ii] * 128 + kuc[ii] * 8);
    #pragma unroll
    for (int ii = 0; ii < 4; ++ii)
        vreg[ii] = *(const bf16x8*)(vbase + vrow[ii] * 4096 + vuc[ii] * 8);
    #pragma unroll
    for (int ii = 0; ii < 4; ++ii)
        *(bf16x8*)&sh.a.Kl[g][0][krow[ii]][kswz[ii] * 8] = kreg[ii];
    #pragma unroll
    for (int ii = 0; ii < 4; ++ii)
        *(bf16x8*)&sh.a.Vl[g][0][vrow[ii]][vswz[ii] * 8] = vreg[ii];
    __syncthreads();

    int p = 0;
    for (int it = 0; it < 32; ++it) {
        // issue next-tile global loads (in flight during compute)
        if (it + 1 < 32) {
            int kv = (it + 1) * 64;
            #pragma unroll
            for (int ii = 0; ii < 4; ++ii)
                kreg[ii] = *(const bf16x8*)(kbase + (kv + krow[ii]) * 128 + kuc[ii] * 8);
            #pragma unroll
            for (int ii = 0; ii < 4; ++ii)
                vreg[ii] = *(const bf16x8*)(vbase + vrow[ii] * 4096 + kv + vuc[ii] * 8);
        }

        // QK^T swapped: p[nt][r] = S[key = nt*16+lg*4+r][qrow = ll]
        float sc[4][4];
        #pragma unroll
        for (int nt = 0; nt < 4; ++nt) {
            f32x4 f = (f32x4){0.f, 0.f, 0.f, 0.f};
            #pragma unroll
            for (int kb = 0; kb < 4; ++kb) {
                bf16x8 kf = *(const bf16x8*)&sh.a.Kl[g][p][nt * 16 + ll][((kb * 4 + lg) ^ sK) * 8];
                f = __builtin_amdgcn_mfma_f32_16x16x32_bf16(kf, qa[kb], f, 0, 0, 0);
            }
            #pragma unroll
            for (int r = 0; r < 4; ++r) sc[nt][r] = f[r];
        }

        // row max for q-row ll (lanes ll, ll+16, ll+32, ll+48 share)
        float mx = sc[0][0];
        #pragma unroll
        for (int nt = 0; nt < 4; ++nt)
            #pragma unroll
            for (int r = 0; r < 4; ++r) mx = fmaxf(mx, sc[nt][r]);
        mx = fmaxf(mx, __shfl_xor(mx, 16, 64));
        mx = fmaxf(mx, __shfl_xor(mx, 32, 64));

        // defer-max (T13): only rescale when some row grew past THR=8
        if (__any(mx - m > 8.f)) {
            float mnew = fmaxf(m, mx);
            float alpha = __expf(m - mnew);
            float arow[4];
            #pragma unroll
            for (int r = 0; r < 4; ++r) arow[r] = __shfl(alpha, lg * 4 + r, 64);
            #pragma unroll
            for (int dt = 0; dt < 8; ++dt)
                #pragma unroll
                for (int r = 0; r < 4; ++r) o[dt][r] *= arow[r];
            lsum *= alpha;
            m = mnew;
        }

        float rsum = 0.f;
        unsigned int pk[4][2];
        #pragma unroll
        for (int nt = 0; nt < 4; ++nt) {
            __bf16 pb[4];
            #pragma unroll
            for (int r = 0; r < 4; ++r) {
                float e = __expf(sc[nt][r] - m);
                pb[r] = (__bf16)e;
                rsum += (float)pb[r];   // sum bf16-rounded P: normalization cancels
            }
            pk[nt][0] = bf16bits(pb[0]) | (bf16bits(pb[1]) << 16);
            pk[nt][1] = bf16bits(pb[2]) | (bf16bits(pb[3]) << 16);
        }
        rsum += __shfl_xor(rsum, 16, 64);
        rsum += __shfl_xor(rsum, 32, 64);
        lsum += rsum;

        // P^T -> PlT[w][qrow=ll][key]; key = nt*16 + lg*4 + r
        #pragma unroll
        for (int nt = 0; nt < 4; ++nt) {
            uint2 u2; u2.x = pk[nt][0]; u2.y = pk[nt][1];
            *(uint2*)&sh.a.PlT[w][ll][nt * 16 + lg * 4] = u2;
        }
        asm volatile("s_waitcnt lgkmcnt(0)" ::: "memory");
        __builtin_amdgcn_sched_barrier(0);

        // PV: O += P @ V
        #pragma unroll
        for (int kc = 0; kc < 2; ++kc) {
            bf16x8 pa = *(const bf16x8*)&sh.a.PlT[w][ll][kc * 32 + lg * 8];
            #pragma unroll
            for (int dt = 0; dt < 8; ++dt) {
                bf16x8 vb = *(const bf16x8*)&sh.a.Vl[g][p][dt * 16 + ll][((kc * 4 + lg) ^ sK) * 8];
                o[dt] = __builtin_amdgcn_mfma_f32_16x16x32_bf16(pa, vb, o[dt], 0, 0, 0);
            }
        }

        // write staged tile into the OTHER buffer (no race: readers use buf p)
        if (it + 1 < 32) {
            #pragma unroll
            for (int ii = 0; ii < 4; ++ii)
                *(bf16x8*)&sh.a.Kl[g][p ^ 1][krow[ii]][kswz[ii] * 8] = kreg[ii];
            #pragma unroll
            for (int ii = 0; ii < 4; ++ii)
                *(bf16x8*)&sh.a.Vl[g][p ^ 1][vrow[ii]][vswz[ii] * 8] = vreg[ii];
        }
        __syncthreads();
        p ^= 1;
    }

    // ---- split-K merge (overlay region; main loop fully done) ----
    if (lg == 0) { sh.b.m_l[g][rb + ll] = m; sh.b.l_l[g][rb + ll] = lsum; }
    __syncthreads();

    float a_own[4], inv[4];
    #pragma unroll
    for (int r = 0; r < 4; ++r) {
        int qr = rb + lg * 4 + r;
        float m0 = sh.b.m_l[0][qr], m1 = sh.b.m_l[1][qr];
        float l0 = sh.b.l_l[0][qr], l1 = sh.b.l_l[1][qr];
        float mst = fmaxf(m0, m1);
        float a0 = __expf(m0 - mst), a1 = __expf(m1 - mst);
        float lst = l0 * a0 + l1 * a1;
        a_own[r] = (g == 0) ? a0 : a1;
        inv[r] = 1.f / lst;
    }
    if (g == 1) {
        #pragma unroll
        for (int dt = 0; dt < 8; ++dt)
            #pragma unroll
            for (int r = 0; r < 4; ++r)
                sh.b.Obuf[rb + lg * 4 + r][dt * 16 + ll] = o[dt][r] * a_own[r];
    }
    __syncthreads();
    if (g == 0) {
        float* ob = out + (long)(b * 4096 + qt * 64) * 128;
        #pragma unroll
        for (int r = 0; r < 4; ++r) {
            int qr = rb + lg * 4 + r;
            #pragma unroll
            for (int dt = 0; dt < 8; ++dt)
                ob[qr * 128 + dt * 16 + ll] =
                    (o[dt][r] * a_own[r] + sh.b.Obuf[qr][dt * 16 + ll]) * inv[r];
        }
    }
}

extern "C" void kernel_launch(void* const* d_in, const int* in_sizes, int n_in,
                              void* d_out, int out_size, void* d_ws, size_t ws_size,
                              hipStream_t stream) {
    (void)in_sizes; (void)n_in; (void)out_size; (void)ws_size;
    const float* x  = (const float*)d_in[0];
    const float* Wq = (const float*)d_in[1];
    const float* bq = (const float*)d_in[2];
    const float* Wk = (const float*)d_in[3];
    const float* bk = (const float*)d_in[4];
    const float* Wv = (const float*)d_in[5];
    const float* bv = (const float*)d_in[6];
    float* out = (float*)d_out;

    __bf16* Q  = (__bf16*)d_ws;                  // 4 MB
    __bf16* K  = Q + NB * SEQ * DIM;             // 4 MB
    __bf16* Vt = K + NB * SEQ * DIM;             // 4 MB
    __bf16* Wh = Vt + NB * SEQ * DIM;            // 96 KB
    __bf16* Wl = Wh + 3 * DIM * DIM;             // 96 KB

    wconv<<<48, 256, 0, stream>>>(Wq, Wk, Wv, Wh, Wl);
    dim3 g1(256, 3), b1(256);
    qkv_proj<<<g1, b1, 0, stream>>>(x, Wh, Wl, bq, bk, bv, Q, K, Vt);
    attn_fwd<<<256, 512, 0, stream>>>(Q, K, Vt, out);
}

// Round 7
// 156.540 us; speedup vs baseline: 1.3273x; 1.3273x over previous
//
#include <hip/hip_runtime.h>
#include <hip/hip_bf16.h>

typedef __bf16 bf16x8 __attribute__((ext_vector_type(8)));
typedef __bf16 bf16x4 __attribute__((ext_vector_type(4)));
typedef float  f32x4  __attribute__((ext_vector_type(4)));

#define NB 4
#define SEQ 4096
#define DIM 128

static __device__ __forceinline__ unsigned int bf16bits(__bf16 h) {
    return (unsigned int)__builtin_bit_cast(unsigned short, h);
}

// ---------------------------------------------------------------------------
// Kernel 0: W fp32 -> (Wh, Wl) bf16 split pair.  Wh = bf16(w), Wl = bf16(w-Wh)
// ---------------------------------------------------------------------------
__global__ __launch_bounds__(256) void wconv(
    const float* __restrict__ Wq, const float* __restrict__ Wk,
    const float* __restrict__ Wv,
    __bf16* __restrict__ Wh, __bf16* __restrict__ Wl)
{
    int idx = blockIdx.x * 256 + threadIdx.x;     // float4 index, 12288 total
    int which = idx >> 12;                        // 4096 float4 per matrix
    int off = (idx & 4095) * 4;
    const float* W = which == 0 ? Wq : (which == 1 ? Wk : Wv);
    float4 v = *(const float4*)(W + off);
    bf16x4 h, lo;
    h[0] = (__bf16)v.x; h[1] = (__bf16)v.y; h[2] = (__bf16)v.z; h[3] = (__bf16)v.w;
    lo[0] = (__bf16)(v.x - (float)h[0]);
    lo[1] = (__bf16)(v.y - (float)h[1]);
    lo[2] = (__bf16)(v.z - (float)h[2]);
    lo[3] = (__bf16)(v.w - (float)h[3]);
    *(bf16x4*)(Wh + which * 16384 + off) = h;
    *(bf16x4*)(Wl + which * 16384 + off) = lo;
}

// ---------------------------------------------------------------------------
// Kernel 1: QKV projection via 3-term split-bf16 MFMA (unchanged from R5).
// ---------------------------------------------------------------------------
__global__ __launch_bounds__(256) void qkv_proj(
    const float* __restrict__ x,
    const __bf16* __restrict__ Whg, const __bf16* __restrict__ Wlg,
    const float* __restrict__ bq, const float* __restrict__ bk,
    const float* __restrict__ bv,
    __bf16* __restrict__ Q, __bf16* __restrict__ K, __bf16* __restrict__ Vt)
{
    __shared__ __bf16 vbuf[64][136];
    const int t  = threadIdx.x;
    const int w  = t >> 6, l = t & 63, lg = l >> 4, ll = l & 15;
    const int rt = blockIdx.x, which = blockIdx.y;

    const __bf16* Wh = Whg + which * 16384;
    const __bf16* Wl = Wlg + which * 16384;
    const float* bias = which == 0 ? bq : (which == 1 ? bk : bv);

    float bfr[8];
    #pragma unroll
    for (int ct = 0; ct < 8; ++ct) bfr[ct] = bias[ct * 16 + ll];

    f32x4 acc[8];
    #pragma unroll
    for (int ct = 0; ct < 8; ++ct) acc[ct] = (f32x4){0.f, 0.f, 0.f, 0.f};

    const float* xrow = x + (rt * 64 + w * 16 + ll) * 128;

    #pragma unroll 1
    for (int kb = 0; kb < 4; ++kb) {
        float4 xa = *(const float4*)(xrow + kb * 32 + lg * 8);
        float4 xb = *(const float4*)(xrow + kb * 32 + lg * 8 + 4);
        float xv[8] = {xa.x, xa.y, xa.z, xa.w, xb.x, xb.y, xb.z, xb.w};
        bf16x8 xh, xl;
        #pragma unroll
        for (int j = 0; j < 8; ++j) {
            __bf16 h = (__bf16)xv[j];
            xh[j] = h;
            xl[j] = (__bf16)(xv[j] - (float)h);
        }
        #pragma unroll
        for (int ct = 0; ct < 8; ++ct) {
            bf16x8 wh = *(const bf16x8*)(Wh + (ct * 16 + ll) * 128 + kb * 32 + lg * 8);
            bf16x8 wl = *(const bf16x8*)(Wl + (ct * 16 + ll) * 128 + kb * 32 + lg * 8);
            acc[ct] = __builtin_amdgcn_mfma_f32_16x16x32_bf16(xh, wh, acc[ct], 0, 0, 0);
            acc[ct] = __builtin_amdgcn_mfma_f32_16x16x32_bf16(xh, wl, acc[ct], 0, 0, 0);
            acc[ct] = __builtin_amdgcn_mfma_f32_16x16x32_bf16(xl, wh, acc[ct], 0, 0, 0);
        }
    }

    const float qscale = 0.08838834764831845f;  // 1/sqrt(128)
    const float scale = (which == 0) ? qscale : 1.0f;
    #pragma unroll
    for (int ct = 0; ct < 8; ++ct)
        #pragma unroll
        for (int r = 0; r < 4; ++r)
            vbuf[w * 16 + lg * 4 + r][ct * 16 + ll] = (__bf16)((acc[ct][r] + bfr[ct]) * scale);
    __syncthreads();

    if (which < 2) {
        __bf16* dst = (which == 0 ? Q : K) + (rt * 64 + (t >> 2)) * 128 + (t & 3) * 32;
        const __bf16* src = &vbuf[t >> 2][(t & 3) * 32];
        #pragma unroll
        for (int i = 0; i < 4; ++i) ((bf16x8*)dst)[i] = ((const bf16x8*)src)[i];
    } else {
        int e = t >> 1, sh = (t & 1) * 32;
        int bb = rt >> 6, sb = (rt & 63) * 64 + sh;
        __bf16 tmp[32];
        #pragma unroll
        for (int j = 0; j < 32; ++j) tmp[j] = vbuf[sh + j][e];
        __bf16* dst = Vt + bb * (128 * 4096) + e * 4096 + sb;
        #pragma unroll
        for (int i = 0; i < 4; ++i) ((bf16x8*)dst)[i] = *(const bf16x8*)&tmp[i * 8];
    }
}

// ---------------------------------------------------------------------------
// Kernel 2: flash attention partial, split-K ACROSS BLOCKS for occupancy.
// grid (256 q-tiles, nsplit), block 256 (4 waves x 16 q-rows, shared K/V tile).
// LDS 40 KB -> 4 blocks/CU; waves on one SIMD come from independent blocks.
// R5 semantics: 2-barrier single-buffer staging, full rescale each iter,
// swapped QK^T (lane scalar softmax state), XOR-swizzled LDS tiles.
// Writes UNNORMALIZED O partial + (m, lsum) per row; merged by attn_merge.
// ---------------------------------------------------------------------------
__global__ __launch_bounds__(256, 4) void attn_fwd(
    const __bf16* __restrict__ Qg,
    const __bf16* __restrict__ Kg,
    const __bf16* __restrict__ Vt,
    float* __restrict__ Op, float* __restrict__ m_p, float* __restrict__ l_p,
    int kv_len)
{
    __shared__ __bf16 Kl[64][128];    // [key][d], 16B units swizzled: u ^= row&7
    __shared__ __bf16 Vl[128][64];    // [d][key], swizzled
    __shared__ __bf16 PlT[4][16][64]; // [wave][qrow][key], 8B subunits swizzled

    const int t  = threadIdx.x;
    const int w  = t >> 6;
    const int l  = t & 63, lg = l >> 4, ll = l & 15;
    const int sK = ll & 7;

    const int bid = blockIdx.x;
    const int b = bid >> 6, qt = bid & 63;
    const int s = blockIdx.y;
    const int rb = w * 16;
    const int qrow0 = qt * 64 + rb;

    bf16x8 qa[4];
    const __bf16* qbase = Qg + (b * 4096 + qrow0 + ll) * 128 + lg * 8;
    #pragma unroll
    for (int kb = 0; kb < 4; ++kb) qa[kb] = *(const bf16x8*)(qbase + kb * 32);

    f32x4 o[8];
    #pragma unroll
    for (int dt = 0; dt < 8; ++dt) o[dt] = (f32x4){0.f, 0.f, 0.f, 0.f};
    float m = -1e30f, lsum = 0.f;

    const __bf16* kbase = Kg + ((long)b * 4096 + s * kv_len) * 128;
    const __bf16* vbase = Vt + (long)b * 128 * 4096 + s * kv_len;

    // staging decomposition (per thread: 4 K units + 4 V units of 16B)
    int krow[4], kuc[4], kswz[4], vrow[4], vuc[4], vswz[4];
    #pragma unroll
    for (int ii = 0; ii < 4; ++ii) {
        int u = t + ii * 256;
        krow[ii] = u >> 4; kuc[ii] = u & 15; kswz[ii] = kuc[ii] ^ (krow[ii] & 7);
        vrow[ii] = u >> 3; vuc[ii] = u & 7;  vswz[ii] = vuc[ii] ^ (vrow[ii] & 7);
    }

    bf16x8 kreg[4], vreg[4];
    // prologue: stage tile 0
    #pragma unroll
    for (int ii = 0; ii < 4; ++ii)
        kreg[ii] = *(const bf16x8*)(kbase + krow[ii] * 128 + kuc[ii] * 8);
    #pragma unroll
    for (int ii = 0; ii < 4; ++ii)
        vreg[ii] = *(const bf16x8*)(vbase + vrow[ii] * 4096 + vuc[ii] * 8);
    #pragma unroll
    for (int ii = 0; ii < 4; ++ii) *(bf16x8*)&Kl[krow[ii]][kswz[ii] * 8] = kreg[ii];
    #pragma unroll
    for (int ii = 0; ii < 4; ++ii) *(bf16x8*)&Vl[vrow[ii]][vswz[ii] * 8] = vreg[ii];
    __syncthreads();

    const int nit = kv_len >> 6;
    for (int it = 0; it < nit; ++it) {
        // issue next-tile global loads (hide under compute)
        if (it + 1 < nit) {
            int kv = (it + 1) * 64;
            #pragma unroll
            for (int ii = 0; ii < 4; ++ii)
                kreg[ii] = *(const bf16x8*)(kbase + (kv + krow[ii]) * 128 + kuc[ii] * 8);
            #pragma unroll
            for (int ii = 0; ii < 4; ++ii)
                vreg[ii] = *(const bf16x8*)(vbase + vrow[ii] * 4096 + kv + vuc[ii] * 8);
        }

        // QK^T swapped: sc[nt][r] = S[key = nt*16+lg*4+r][qrow = ll]
        float sc[4][4];
        #pragma unroll
        for (int nt = 0; nt < 4; ++nt) {
            f32x4 f = (f32x4){0.f, 0.f, 0.f, 0.f};
            #pragma unroll
            for (int kb = 0; kb < 4; ++kb) {
                bf16x8 kf = *(const bf16x8*)&Kl[nt * 16 + ll][((kb * 4 + lg) ^ sK) * 8];
                f = __builtin_amdgcn_mfma_f32_16x16x32_bf16(kf, qa[kb], f, 0, 0, 0);
            }
            #pragma unroll
            for (int r = 0; r < 4; ++r) sc[nt][r] = f[r];
        }

        // row stats for q-row ll (lanes ll, ll+16, ll+32, ll+48 share)
        float mx = sc[0][0];
        #pragma unroll
        for (int nt = 0; nt < 4; ++nt)
            #pragma unroll
            for (int r = 0; r < 4; ++r) mx = fmaxf(mx, sc[nt][r]);
        mx = fmaxf(mx, __shfl_xor(mx, 16, 64));
        mx = fmaxf(mx, __shfl_xor(mx, 32, 64));
        float mnew = fmaxf(m, mx);
        float alpha = __expf(m - mnew);

        float rsum = 0.f;
        unsigned int pk[4][2];
        #pragma unroll
        for (int nt = 0; nt < 4; ++nt) {
            __bf16 pb[4];
            #pragma unroll
            for (int r = 0; r < 4; ++r) {
                float e = __expf(sc[nt][r] - mnew);
                pb[r] = (__bf16)e;
                rsum += (float)pb[r];   // sum bf16-rounded P: normalization cancels
            }
            pk[nt][0] = bf16bits(pb[0]) | (bf16bits(pb[1]) << 16);
            pk[nt][1] = bf16bits(pb[2]) | (bf16bits(pb[3]) << 16);
        }
        rsum += __shfl_xor(rsum, 16, 64);
        rsum += __shfl_xor(rsum, 32, 64);
        lsum = lsum * alpha + rsum;
        m = mnew;

        // P^T -> PlT (swizzled 8B subunits): subunit = (nt*4+lg) ^ ((ll&7)<<1)
        #pragma unroll
        for (int nt = 0; nt < 4; ++nt) {
            uint2 u2; u2.x = pk[nt][0]; u2.y = pk[nt][1];
            *(uint2*)&PlT[w][ll][((nt * 4 + lg) ^ (sK << 1)) * 4] = u2;
        }
        asm volatile("s_waitcnt lgkmcnt(0)" ::: "memory");
        __builtin_amdgcn_sched_barrier(0);

        // rescale O: alpha for q-rows lg*4+r held at lanes lg*4+r
        float arow[4];
        #pragma unroll
        for (int r = 0; r < 4; ++r) arow[r] = __shfl(alpha, lg * 4 + r, 64);
        #pragma unroll
        for (int dt = 0; dt < 8; ++dt)
            #pragma unroll
            for (int r = 0; r < 4; ++r) o[dt][r] *= arow[r];

        // PV: O += P @ V
        #pragma unroll
        for (int kc = 0; kc < 2; ++kc) {
            bf16x8 pa = *(const bf16x8*)&PlT[w][ll][((kc * 4 + lg) ^ sK) * 8];
            #pragma unroll
            for (int dt = 0; dt < 8; ++dt) {
                bf16x8 vb = *(const bf16x8*)&Vl[dt * 16 + ll][((kc * 4 + lg) ^ sK) * 8];
                o[dt] = __builtin_amdgcn_mfma_f32_16x16x32_bf16(pa, vb, o[dt], 0, 0, 0);
            }
        }

        __syncthreads();            // all waves done reading tile `it`
        if (it + 1 < nit) {
            #pragma unroll
            for (int ii = 0; ii < 4; ++ii) *(bf16x8*)&Kl[krow[ii]][kswz[ii] * 8] = kreg[ii];
            #pragma unroll
            for (int ii = 0; ii < 4; ++ii) *(bf16x8*)&Vl[vrow[ii]][vswz[ii] * 8] = vreg[ii];
        }
        __syncthreads();            // staged writes visible
    }

    // epilogue: unnormalized partial O + per-row (m, lsum)
    long rowbase = (long)s * (NB * SEQ) + b * 4096 + qt * 64 + rb;
    float* op = Op + rowbase * 128;
    #pragma unroll
    for (int r = 0; r < 4; ++r)
        #pragma unroll
        for (int dt = 0; dt < 8; ++dt)
            op[(lg * 4 + r) * 128 + dt * 16 + ll] = o[dt][r];
    if (lg == 0) {
        m_p[rowbase + ll] = m;
        l_p[rowbase + ll] = lsum;
    }
}

// ---------------------------------------------------------------------------
// Kernel 3: merge split-K partials.  grid 256 x 256 thr; 64 rows/block.
// out[row] = sum_s Op[s][row]*exp(m_s-M) / sum_s l_s*exp(m_s-M)
// ---------------------------------------------------------------------------
__global__ __launch_bounds__(256) void attn_merge(
    const float* __restrict__ Op, const float* __restrict__ m_p,
    const float* __restrict__ l_p, float* __restrict__ out, int nsplit)
{
    const int t = threadIdx.x;
    const int base_row = blockIdx.x * 64;
    #pragma unroll 1
    for (int k = 0; k < 8; ++k) {
        int u = t + k * 256;                 // float4 unit within 64x128 tile
        int row = base_row + (u >> 5);
        int dq = u & 31;
        float M = -1e30f;
        for (int sp = 0; sp < nsplit; ++sp)
            M = fmaxf(M, m_p[(long)sp * (NB * SEQ) + row]);
        float L = 0.f;
        float4 acc = {0.f, 0.f, 0.f, 0.f};
        for (int sp = 0; sp < nsplit; ++sp) {
            long rb2 = (long)sp * (NB * SEQ) + row;
            float a = __expf(m_p[rb2] - M);
            L += l_p[rb2] * a;
            float4 v = *(const float4*)(Op + rb2 * 128 + dq * 4);
            acc.x += v.x * a; acc.y += v.y * a; acc.z += v.z * a; acc.w += v.w * a;
        }
        float inv = 1.f / L;
        float4 r4 = {acc.x * inv, acc.y * inv, acc.z * inv, acc.w * inv};
        *(float4*)(out + (long)row * 128 + dq * 4) = r4;
    }
}

extern "C" void kernel_launch(void* const* d_in, const int* in_sizes, int n_in,
                              void* d_out, int out_size, void* d_ws, size_t ws_size,
                              hipStream_t stream) {
    (void)in_sizes; (void)n_in; (void)out_size;
    const float* x  = (const float*)d_in[0];
    const float* Wq = (const float*)d_in[1];
    const float* bq = (const float*)d_in[2];
    const float* Wk = (const float*)d_in[3];
    const float* bk = (const float*)d_in[4];
    const float* Wv = (const float*)d_in[5];
    const float* bv = (const float*)d_in[6];
    float* out = (float*)d_out;

    const size_t qkv_elems = (size_t)NB * SEQ * DIM;          // 2 MB elems
    char* p = (char*)d_ws;
    __bf16* Q  = (__bf16*)p;        p += qkv_elems * 2;       // 4 MB
    __bf16* K  = (__bf16*)p;        p += qkv_elems * 2;       // 4 MB
    __bf16* Vt = (__bf16*)p;        p += qkv_elems * 2;       // 4 MB
    __bf16* Wh = (__bf16*)p;        p += 3 * DIM * DIM * 2;   // 96 KB
    __bf16* Wl = (__bf16*)p;        p += 3 * DIM * DIM * 2;   // 96 KB
    size_t used = (size_t)(p - (char*)d_ws);

    // partials: per split 8 MB O + 64 KB m + 64 KB l
    const size_t per_split = (size_t)NB * SEQ * DIM * 4 + 2 * (size_t)NB * SEQ * 4;
    int nsplit = 4;
    while (nsplit > 1 && used + (size_t)nsplit * per_split > ws_size) nsplit >>= 1;

    float* Op  = (float*)p;                      p += (size_t)nsplit * NB * SEQ * DIM * 4;
    float* m_p = (float*)p;                      p += (size_t)nsplit * NB * SEQ * 4;
    float* l_p = (float*)p;

    wconv<<<48, 256, 0, stream>>>(Wq, Wk, Wv, Wh, Wl);
    dim3 g1(256, 3), b1(256);
    qkv_proj<<<g1, b1, 0, stream>>>(x, Wh, Wl, bq, bk, bv, Q, K, Vt);
    dim3 g2(256, nsplit);
    attn_fwd<<<g2, 256, 0, stream>>>(Q, K, Vt, Op, m_p, l_p, SEQ / nsplit);
    attn_merge<<<256, 256, 0, stream>>>(Op, m_p, l_p, out, nsplit);
}

// Round 8
// 150.117 us; speedup vs baseline: 1.3841x; 1.0428x over previous
//
#include <hip/hip_runtime.h>
#include <hip/hip_bf16.h>

typedef __bf16 bf16x8 __attribute__((ext_vector_type(8)));
typedef __bf16 bf16x4 __attribute__((ext_vector_type(4)));
typedef float  f32x4  __attribute__((ext_vector_type(4)));

#define NB 4
#define SEQ 4096
#define DIM 128

static __device__ __forceinline__ unsigned int bf16bits(__bf16 h) {
    return (unsigned int)__builtin_bit_cast(unsigned short, h);
}

// ---------------------------------------------------------------------------
// Kernel 0: W fp32 -> (Wh, Wl) bf16 split pair.  Wh = bf16(w), Wl = bf16(w-Wh)
// ---------------------------------------------------------------------------
__global__ __launch_bounds__(256) void wconv(
    const float* __restrict__ Wq, const float* __restrict__ Wk,
    const float* __restrict__ Wv,
    __bf16* __restrict__ Wh, __bf16* __restrict__ Wl)
{
    int idx = blockIdx.x * 256 + threadIdx.x;     // float4 index, 12288 total
    int which = idx >> 12;                        // 4096 float4 per matrix
    int off = (idx & 4095) * 4;
    const float* W = which == 0 ? Wq : (which == 1 ? Wk : Wv);
    float4 v = *(const float4*)(W + off);
    bf16x4 h, lo;
    h[0] = (__bf16)v.x; h[1] = (__bf16)v.y; h[2] = (__bf16)v.z; h[3] = (__bf16)v.w;
    lo[0] = (__bf16)(v.x - (float)h[0]);
    lo[1] = (__bf16)(v.y - (float)h[1]);
    lo[2] = (__bf16)(v.z - (float)h[2]);
    lo[3] = (__bf16)(v.w - (float)h[3]);
    *(bf16x4*)(Wh + which * 16384 + off) = h;
    *(bf16x4*)(Wl + which * 16384 + off) = lo;
}

// ---------------------------------------------------------------------------
// Kernel 1: QKV projection via 3-term split-bf16 MFMA (unchanged from R5).
// ---------------------------------------------------------------------------
__global__ __launch_bounds__(256) void qkv_proj(
    const float* __restrict__ x,
    const __bf16* __restrict__ Whg, const __bf16* __restrict__ Wlg,
    const float* __restrict__ bq, const float* __restrict__ bk,
    const float* __restrict__ bv,
    __bf16* __restrict__ Q, __bf16* __restrict__ K, __bf16* __restrict__ Vt)
{
    __shared__ __bf16 vbuf[64][136];
    const int t  = threadIdx.x;
    const int w  = t >> 6, l = t & 63, lg = l >> 4, ll = l & 15;
    const int rt = blockIdx.x, which = blockIdx.y;

    const __bf16* Wh = Whg + which * 16384;
    const __bf16* Wl = Wlg + which * 16384;
    const float* bias = which == 0 ? bq : (which == 1 ? bk : bv);

    float bfr[8];
    #pragma unroll
    for (int ct = 0; ct < 8; ++ct) bfr[ct] = bias[ct * 16 + ll];

    f32x4 acc[8];
    #pragma unroll
    for (int ct = 0; ct < 8; ++ct) acc[ct] = (f32x4){0.f, 0.f, 0.f, 0.f};

    const float* xrow = x + (rt * 64 + w * 16 + ll) * 128;

    #pragma unroll 1
    for (int kb = 0; kb < 4; ++kb) {
        float4 xa = *(const float4*)(xrow + kb * 32 + lg * 8);
        float4 xb = *(const float4*)(xrow + kb * 32 + lg * 8 + 4);
        float xv[8] = {xa.x, xa.y, xa.z, xa.w, xb.x, xb.y, xb.z, xb.w};
        bf16x8 xh, xl;
        #pragma unroll
        for (int j = 0; j < 8; ++j) {
            __bf16 h = (__bf16)xv[j];
            xh[j] = h;
            xl[j] = (__bf16)(xv[j] - (float)h);
        }
        #pragma unroll
        for (int ct = 0; ct < 8; ++ct) {
            bf16x8 wh = *(const bf16x8*)(Wh + (ct * 16 + ll) * 128 + kb * 32 + lg * 8);
            bf16x8 wl = *(const bf16x8*)(Wl + (ct * 16 + ll) * 128 + kb * 32 + lg * 8);
            acc[ct] = __builtin_amdgcn_mfma_f32_16x16x32_bf16(xh, wh, acc[ct], 0, 0, 0);
            acc[ct] = __builtin_amdgcn_mfma_f32_16x16x32_bf16(xh, wl, acc[ct], 0, 0, 0);
            acc[ct] = __builtin_amdgcn_mfma_f32_16x16x32_bf16(xl, wh, acc[ct], 0, 0, 0);
        }
    }

    const float qscale = 0.08838834764831845f;  // 1/sqrt(128)
    const float scale = (which == 0) ? qscale : 1.0f;
    #pragma unroll
    for (int ct = 0; ct < 8; ++ct)
        #pragma unroll
        for (int r = 0; r < 4; ++r)
            vbuf[w * 16 + lg * 4 + r][ct * 16 + ll] = (__bf16)((acc[ct][r] + bfr[ct]) * scale);
    __syncthreads();

    if (which < 2) {
        __bf16* dst = (which == 0 ? Q : K) + (rt * 64 + (t >> 2)) * 128 + (t & 3) * 32;
        const __bf16* src = &vbuf[t >> 2][(t & 3) * 32];
        #pragma unroll
        for (int i = 0; i < 4; ++i) ((bf16x8*)dst)[i] = ((const bf16x8*)src)[i];
    } else {
        int e = t >> 1, sh = (t & 1) * 32;
        int bb = rt >> 6, sb = (rt & 63) * 64 + sh;
        __bf16 tmp[32];
        #pragma unroll
        for (int j = 0; j < 32; ++j) tmp[j] = vbuf[sh + j][e];
        __bf16* dst = Vt + bb * (128 * 4096) + e * 4096 + sb;
        #pragma unroll
        for (int i = 0; i < 4; ++i) ((bf16x8*)dst)[i] = *(const bf16x8*)&tmp[i * 8];
    }
}

// ---------------------------------------------------------------------------
// Kernel 2: flash attention partial, split-K across blocks (R7) + R8's ONE
// change: XCD-bijective block swizzle. HW assigns XCD = linear_id % 8
// (m09/m157); we remap lin -> v = (lin&7)*chunk + (lin>>3) and decode v
// s-major so each XCD owns CONTIGUOUS (split, batch) chunks -> its K/V
// quarters stay L2-resident instead of all-XCDs-fetch-everything.
// ---------------------------------------------------------------------------
__global__ __launch_bounds__(256, 4) void attn_fwd(
    const __bf16* __restrict__ Qg,
    const __bf16* __restrict__ Kg,
    const __bf16* __restrict__ Vt,
    float* __restrict__ Op, float* __restrict__ m_p, float* __restrict__ l_p,
    int kv_len)
{
    __shared__ __bf16 Kl[64][128];    // [key][d], 16B units swizzled: u ^= row&7
    __shared__ __bf16 Vl[128][64];    // [d][key], swizzled
    __shared__ __bf16 PlT[4][16][64]; // [wave][qrow][key], 8B subunits swizzled

    const int t  = threadIdx.x;
    const int w  = t >> 6;
    const int l  = t & 63, lg = l >> 4, ll = l & 15;
    const int sK = ll & 7;

    // ---- XCD-aware bijective swizzle (nwg = 256*nsplit, divisible by 8) ----
    const int nwg = gridDim.x * gridDim.y;
    const int lin = blockIdx.x + gridDim.x * blockIdx.y;
    const int chunk = nwg >> 3;
    const int v = (lin & 7) * chunk + (lin >> 3);
    // v = (s*NB + b)*64 + qt  (s-major: one XCD's chunk spans few (s,b) pairs)
    const int qt = v & 63;
    const int sb = v >> 6;
    const int b  = sb & (NB - 1);
    const int s  = sb >> 2;

    const int rb = w * 16;
    const int qrow0 = qt * 64 + rb;

    bf16x8 qa[4];
    const __bf16* qbase = Qg + (b * 4096 + qrow0 + ll) * 128 + lg * 8;
    #pragma unroll
    for (int kb = 0; kb < 4; ++kb) qa[kb] = *(const bf16x8*)(qbase + kb * 32);

    f32x4 o[8];
    #pragma unroll
    for (int dt = 0; dt < 8; ++dt) o[dt] = (f32x4){0.f, 0.f, 0.f, 0.f};
    float m = -1e30f, lsum = 0.f;

    const __bf16* kbase = Kg + ((long)b * 4096 + s * kv_len) * 128;
    const __bf16* vbase = Vt + (long)b * 128 * 4096 + s * kv_len;

    // staging decomposition (per thread: 4 K units + 4 V units of 16B)
    int krow[4], kuc[4], kswz[4], vrow[4], vuc[4], vswz[4];
    #pragma unroll
    for (int ii = 0; ii < 4; ++ii) {
        int u = t + ii * 256;
        krow[ii] = u >> 4; kuc[ii] = u & 15; kswz[ii] = kuc[ii] ^ (krow[ii] & 7);
        vrow[ii] = u >> 3; vuc[ii] = u & 7;  vswz[ii] = vuc[ii] ^ (vrow[ii] & 7);
    }

    bf16x8 kreg[4], vreg[4];
    // prologue: stage tile 0
    #pragma unroll
    for (int ii = 0; ii < 4; ++ii)
        kreg[ii] = *(const bf16x8*)(kbase + krow[ii] * 128 + kuc[ii] * 8);
    #pragma unroll
    for (int ii = 0; ii < 4; ++ii)
        vreg[ii] = *(const bf16x8*)(vbase + vrow[ii] * 4096 + vuc[ii] * 8);
    #pragma unroll
    for (int ii = 0; ii < 4; ++ii) *(bf16x8*)&Kl[krow[ii]][kswz[ii] * 8] = kreg[ii];
    #pragma unroll
    for (int ii = 0; ii < 4; ++ii) *(bf16x8*)&Vl[vrow[ii]][vswz[ii] * 8] = vreg[ii];
    __syncthreads();

    const int nit = kv_len >> 6;
    for (int it = 0; it < nit; ++it) {
        // issue next-tile global loads (hide under compute)
        if (it + 1 < nit) {
            int kv = (it + 1) * 64;
            #pragma unroll
            for (int ii = 0; ii < 4; ++ii)
                kreg[ii] = *(const bf16x8*)(kbase + (kv + krow[ii]) * 128 + kuc[ii] * 8);
            #pragma unroll
            for (int ii = 0; ii < 4; ++ii)
                vreg[ii] = *(const bf16x8*)(vbase + vrow[ii] * 4096 + kv + vuc[ii] * 8);
        }

        // QK^T swapped: sc[nt][r] = S[key = nt*16+lg*4+r][qrow = ll]
        float sc[4][4];
        #pragma unroll
        for (int nt = 0; nt < 4; ++nt) {
            f32x4 f = (f32x4){0.f, 0.f, 0.f, 0.f};
            #pragma unroll
            for (int kb = 0; kb < 4; ++kb) {
                bf16x8 kf = *(const bf16x8*)&Kl[nt * 16 + ll][((kb * 4 + lg) ^ sK) * 8];
                f = __builtin_amdgcn_mfma_f32_16x16x32_bf16(kf, qa[kb], f, 0, 0, 0);
            }
            #pragma unroll
            for (int r = 0; r < 4; ++r) sc[nt][r] = f[r];
        }

        // row stats for q-row ll (lanes ll, ll+16, ll+32, ll+48 share)
        float mx = sc[0][0];
        #pragma unroll
        for (int nt = 0; nt < 4; ++nt)
            #pragma unroll
            for (int r = 0; r < 4; ++r) mx = fmaxf(mx, sc[nt][r]);
        mx = fmaxf(mx, __shfl_xor(mx, 16, 64));
        mx = fmaxf(mx, __shfl_xor(mx, 32, 64));
        float mnew = fmaxf(m, mx);
        float alpha = __expf(m - mnew);

        float rsum = 0.f;
        unsigned int pk[4][2];
        #pragma unroll
        for (int nt = 0; nt < 4; ++nt) {
            __bf16 pb[4];
            #pragma unroll
            for (int r = 0; r < 4; ++r) {
                float e = __expf(sc[nt][r] - mnew);
                pb[r] = (__bf16)e;
                rsum += (float)pb[r];   // sum bf16-rounded P: normalization cancels
            }
            pk[nt][0] = bf16bits(pb[0]) | (bf16bits(pb[1]) << 16);
            pk[nt][1] = bf16bits(pb[2]) | (bf16bits(pb[3]) << 16);
        }
        rsum += __shfl_xor(rsum, 16, 64);
        rsum += __shfl_xor(rsum, 32, 64);
        lsum = lsum * alpha + rsum;
        m = mnew;

        // P^T -> PlT (swizzled 8B subunits): subunit = (nt*4+lg) ^ ((ll&7)<<1)
        #pragma unroll
        for (int nt = 0; nt < 4; ++nt) {
            uint2 u2; u2.x = pk[nt][0]; u2.y = pk[nt][1];
            *(uint2*)&PlT[w][ll][((nt * 4 + lg) ^ (sK << 1)) * 4] = u2;
        }
        asm volatile("s_waitcnt lgkmcnt(0)" ::: "memory");
        __builtin_amdgcn_sched_barrier(0);

        // rescale O: alpha for q-rows lg*4+r held at lanes lg*4+r
        float arow[4];
        #pragma unroll
        for (int r = 0; r < 4; ++r) arow[r] = __shfl(alpha, lg * 4 + r, 64);
        #pragma unroll
        for (int dt = 0; dt < 8; ++dt)
            #pragma unroll
            for (int r = 0; r < 4; ++r) o[dt][r] *= arow[r];

        // PV: O += P @ V
        #pragma unroll
        for (int kc = 0; kc < 2; ++kc) {
            bf16x8 pa = *(const bf16x8*)&PlT[w][ll][((kc * 4 + lg) ^ sK) * 8];
            #pragma unroll
            for (int dt = 0; dt < 8; ++dt) {
                bf16x8 vb = *(const bf16x8*)&Vl[dt * 16 + ll][((kc * 4 + lg) ^ sK) * 8];
                o[dt] = __builtin_amdgcn_mfma_f32_16x16x32_bf16(pa, vb, o[dt], 0, 0, 0);
            }
        }

        __syncthreads();            // all waves done reading tile `it`
        if (it + 1 < nit) {
            #pragma unroll
            for (int ii = 0; ii < 4; ++ii) *(bf16x8*)&Kl[krow[ii]][kswz[ii] * 8] = kreg[ii];
            #pragma unroll
            for (int ii = 0; ii < 4; ++ii) *(bf16x8*)&Vl[vrow[ii]][vswz[ii] * 8] = vreg[ii];
        }
        __syncthreads();            // staged writes visible
    }

    // epilogue: unnormalized partial O + per-row (m, lsum)
    long rowbase = (long)s * (NB * SEQ) + b * 4096 + qt * 64 + rb;
    float* op = Op + rowbase * 128;
    #pragma unroll
    for (int r = 0; r < 4; ++r)
        #pragma unroll
        for (int dt = 0; dt < 8; ++dt)
            op[(lg * 4 + r) * 128 + dt * 16 + ll] = o[dt][r];
    if (lg == 0) {
        m_p[rowbase + ll] = m;
        l_p[rowbase + ll] = lsum;
    }
}

// ---------------------------------------------------------------------------
// Kernel 3: merge split-K partials.  grid 256 x 256 thr; 64 rows/block.
// out[row] = sum_s Op[s][row]*exp(m_s-M) / sum_s l_s*exp(m_s-M)
// ---------------------------------------------------------------------------
__global__ __launch_bounds__(256) void attn_merge(
    const float* __restrict__ Op, const float* __restrict__ m_p,
    const float* __restrict__ l_p, float* __restrict__ out, int nsplit)
{
    const int t = threadIdx.x;
    const int base_row = blockIdx.x * 64;
    #pragma unroll 1
    for (int k = 0; k < 8; ++k) {
        int u = t + k * 256;                 // float4 unit within 64x128 tile
        int row = base_row + (u >> 5);
        int dq = u & 31;
        float M = -1e30f;
        for (int sp = 0; sp < nsplit; ++sp)
            M = fmaxf(M, m_p[(long)sp * (NB * SEQ) + row]);
        float L = 0.f;
        float4 acc = {0.f, 0.f, 0.f, 0.f};
        for (int sp = 0; sp < nsplit; ++sp) {
            long rb2 = (long)sp * (NB * SEQ) + row;
            float a = __expf(m_p[rb2] - M);
            L += l_p[rb2] * a;
            float4 v = *(const float4*)(Op + rb2 * 128 + dq * 4);
            acc.x += v.x * a; acc.y += v.y * a; acc.z += v.z * a; acc.w += v.w * a;
        }
        float inv = 1.f / L;
        float4 r4 = {acc.x * inv, acc.y * inv, acc.z * inv, acc.w * inv};
        *(float4*)(out + (long)row * 128 + dq * 4) = r4;
    }
}

extern "C" void kernel_launch(void* const* d_in, const int* in_sizes, int n_in,
                              void* d_out, int out_size, void* d_ws, size_t ws_size,
                              hipStream_t stream) {
    (void)in_sizes; (void)n_in; (void)out_size;
    const float* x  = (const float*)d_in[0];
    const float* Wq = (const float*)d_in[1];
    const float* bq = (const float*)d_in[2];
    const float* Wk = (const float*)d_in[3];
    const float* bk = (const float*)d_in[4];
    const float* Wv = (const float*)d_in[5];
    const float* bv = (const float*)d_in[6];
    float* out = (float*)d_out;

    const size_t qkv_elems = (size_t)NB * SEQ * DIM;          // 2 MB elems
    char* p = (char*)d_ws;
    __bf16* Q  = (__bf16*)p;        p += qkv_elems * 2;       // 4 MB
    __bf16* K  = (__bf16*)p;        p += qkv_elems * 2;       // 4 MB
    __bf16* Vt = (__bf16*)p;        p += qkv_elems * 2;       // 4 MB
    __bf16* Wh = (__bf16*)p;        p += 3 * DIM * DIM * 2;   // 96 KB
    __bf16* Wl = (__bf16*)p;        p += 3 * DIM * DIM * 2;   // 96 KB
    size_t used = (size_t)(p - (char*)d_ws);

    // partials: per split 8 MB O + 64 KB m + 64 KB l
    const size_t per_split = (size_t)NB * SEQ * DIM * 4 + 2 * (size_t)NB * SEQ * 4;
    int nsplit = 4;
    while (nsplit > 1 && used + (size_t)nsplit * per_split > ws_size) nsplit >>= 1;

    float* Op  = (float*)p;                      p += (size_t)nsplit * NB * SEQ * DIM * 4;
    float* m_p = (float*)p;                      p += (size_t)nsplit * NB * SEQ * 4;
    float* l_p = (float*)p;

    wconv<<<48, 256, 0, stream>>>(Wq, Wk, Wv, Wh, Wl);
    dim3 g1(256, 3), b1(256);
    qkv_proj<<<g1, b1, 0, stream>>>(x, Wh, Wl, bq, bk, bv, Q, K, Vt);
    dim3 g2(256, nsplit);
    attn_fwd<<<g2, 256, 0, stream>>>(Q, K, Vt, Op, m_p, l_p, SEQ / nsplit);
    attn_merge<<<256, 256, 0, stream>>>(Op, m_p, l_p, out, nsplit);
}

// Round 9
// 117.273 us; speedup vs baseline: 1.7717x; 1.2801x over previous
//
#include <hip/hip_runtime.h>
#include <hip/hip_bf16.h>

typedef __bf16 bf16x8 __attribute__((ext_vector_type(8)));
typedef __bf16 bf16x4 __attribute__((ext_vector_type(4)));
typedef float  f32x4  __attribute__((ext_vector_type(4)));

#define NB 4
#define SEQ 4096
#define DIM 128

static __device__ __forceinline__ unsigned int bf16bits(__bf16 h) {
    return (unsigned int)__builtin_bit_cast(unsigned short, h);
}

// global -> LDS direct copy, 16B per lane; LDS dest is wave-uniform base,
// HW writes lane i at base + i*16 (m104). Global src is per-lane (m173).
#define GLOAD_LDS16(g, s) __builtin_amdgcn_global_load_lds(                    \
    (const __attribute__((address_space(1))) void*)(g),                        \
    (__attribute__((address_space(3))) void*)(s), 16, 0, 0)

// ---------------------------------------------------------------------------
// Kernel 0: W fp32 -> (Wh, Wl) bf16 split pair.  Wh = bf16(w), Wl = bf16(w-Wh)
// ---------------------------------------------------------------------------
__global__ __launch_bounds__(256) void wconv(
    const float* __restrict__ Wq, const float* __restrict__ Wk,
    const float* __restrict__ Wv,
    __bf16* __restrict__ Wh, __bf16* __restrict__ Wl)
{
    int idx = blockIdx.x * 256 + threadIdx.x;     // float4 index, 12288 total
    int which = idx >> 12;                        // 4096 float4 per matrix
    int off = (idx & 4095) * 4;
    const float* W = which == 0 ? Wq : (which == 1 ? Wk : Wv);
    float4 v = *(const float4*)(W + off);
    bf16x4 h, lo;
    h[0] = (__bf16)v.x; h[1] = (__bf16)v.y; h[2] = (__bf16)v.z; h[3] = (__bf16)v.w;
    lo[0] = (__bf16)(v.x - (float)h[0]);
    lo[1] = (__bf16)(v.y - (float)h[1]);
    lo[2] = (__bf16)(v.z - (float)h[2]);
    lo[3] = (__bf16)(v.w - (float)h[3]);
    *(bf16x4*)(Wh + which * 16384 + off) = h;
    *(bf16x4*)(Wl + which * 16384 + off) = lo;
}

// ---------------------------------------------------------------------------
// Kernel 1: QKV projection via 3-term split-bf16 MFMA (unchanged from R5).
// ---------------------------------------------------------------------------
__global__ __launch_bounds__(256) void qkv_proj(
    const float* __restrict__ x,
    const __bf16* __restrict__ Whg, const __bf16* __restrict__ Wlg,
    const float* __restrict__ bq, const float* __restrict__ bk,
    const float* __restrict__ bv,
    __bf16* __restrict__ Q, __bf16* __restrict__ K, __bf16* __restrict__ Vt)
{
    __shared__ __bf16 vbuf[64][136];
    const int t  = threadIdx.x;
    const int w  = t >> 6, l = t & 63, lg = l >> 4, ll = l & 15;
    const int rt = blockIdx.x, which = blockIdx.y;

    const __bf16* Wh = Whg + which * 16384;
    const __bf16* Wl = Wlg + which * 16384;
    const float* bias = which == 0 ? bq : (which == 1 ? bk : bv);

    float bfr[8];
    #pragma unroll
    for (int ct = 0; ct < 8; ++ct) bfr[ct] = bias[ct * 16 + ll];

    f32x4 acc[8];
    #pragma unroll
    for (int ct = 0; ct < 8; ++ct) acc[ct] = (f32x4){0.f, 0.f, 0.f, 0.f};

    const float* xrow = x + (rt * 64 + w * 16 + ll) * 128;

    #pragma unroll 1
    for (int kb = 0; kb < 4; ++kb) {
        float4 xa = *(const float4*)(xrow + kb * 32 + lg * 8);
        float4 xb = *(const float4*)(xrow + kb * 32 + lg * 8 + 4);
        float xv[8] = {xa.x, xa.y, xa.z, xa.w, xb.x, xb.y, xb.z, xb.w};
        bf16x8 xh, xl;
        #pragma unroll
        for (int j = 0; j < 8; ++j) {
            __bf16 h = (__bf16)xv[j];
            xh[j] = h;
            xl[j] = (__bf16)(xv[j] - (float)h);
        }
        #pragma unroll
        for (int ct = 0; ct < 8; ++ct) {
            bf16x8 wh = *(const bf16x8*)(Wh + (ct * 16 + ll) * 128 + kb * 32 + lg * 8);
            bf16x8 wl = *(const bf16x8*)(Wl + (ct * 16 + ll) * 128 + kb * 32 + lg * 8);
            acc[ct] = __builtin_amdgcn_mfma_f32_16x16x32_bf16(xh, wh, acc[ct], 0, 0, 0);
            acc[ct] = __builtin_amdgcn_mfma_f32_16x16x32_bf16(xh, wl, acc[ct], 0, 0, 0);
            acc[ct] = __builtin_amdgcn_mfma_f32_16x16x32_bf16(xl, wh, acc[ct], 0, 0, 0);
        }
    }

    const float qscale = 0.08838834764831845f;  // 1/sqrt(128)
    const float scale = (which == 0) ? qscale : 1.0f;
    #pragma unroll
    for (int ct = 0; ct < 8; ++ct)
        #pragma unroll
        for (int r = 0; r < 4; ++r)
            vbuf[w * 16 + lg * 4 + r][ct * 16 + ll] = (__bf16)((acc[ct][r] + bfr[ct]) * scale);
    __syncthreads();

    if (which < 2) {
        __bf16* dst = (which == 0 ? Q : K) + (rt * 64 + (t >> 2)) * 128 + (t & 3) * 32;
        const __bf16* src = &vbuf[t >> 2][(t & 3) * 32];
        #pragma unroll
        for (int i = 0; i < 4; ++i) ((bf16x8*)dst)[i] = ((const bf16x8*)src)[i];
    } else {
        int e = t >> 1, sh = (t & 1) * 32;
        int bb = rt >> 6, sb = (rt & 63) * 64 + sh;
        __bf16 tmp[32];
        #pragma unroll
        for (int j = 0; j < 32; ++j) tmp[j] = vbuf[sh + j][e];
        __bf16* dst = Vt + bb * (128 * 4096) + e * 4096 + sb;
        #pragma unroll
        for (int i = 0; i < 4; ++i) ((bf16x8*)dst)[i] = *(const bf16x8*)&tmp[i * 8];
    }
}

// ---------------------------------------------------------------------------
// Kernel 2: flash attention partial. R9 change: 2x q-row register blocking
// (wave owns 32 q-rows; each K/V LDS fragment feeds 2 MFMAs) + global_load_lds
// staging (pre-swizzled SOURCE, linear LDS dest -> no staging VGPRs).
// Block = 4 waves x 32 q = 128 q-rows. grid (128, nsplit), XCD-chunk swizzle.
// Single LDS buffer, 2 barriers/iter; cross-block TLP hides the stage stall.
// ---------------------------------------------------------------------------
__global__ __launch_bounds__(256, 3) void attn_fwd(
    const __bf16* __restrict__ Qg,
    const __bf16* __restrict__ Kg,
    const __bf16* __restrict__ Vt,
    float* __restrict__ Op, float* __restrict__ m_p, float* __restrict__ l_p,
    int kv_len)
{
    __shared__ __align__(16) __bf16 Kl[64][128];     // [key][d], units swizzled u^=(row&7)
    __shared__ __align__(16) __bf16 Vl[128][64];     // [d][key], swizzled
    __shared__ __align__(16) __bf16 PlT[4][2][16][64]; // [wave][h][qrow][key]

    const int t  = threadIdx.x;
    const int w  = t >> 6;
    const int l  = t & 63, lg = l >> 4, ll = l & 15;
    const int sK = ll & 7;

    // ---- XCD-aware bijective swizzle (nwg = 128*nsplit, divisible by 8) ----
    const int nwg = gridDim.x * gridDim.y;
    const int lin = blockIdx.x + gridDim.x * blockIdx.y;
    const int chunk = nwg >> 3;
    const int v = (lin & 7) * chunk + (lin >> 3);
    const int qt = v & 31;
    const int b  = (v >> 5) & 3;
    const int s  = v >> 7;

    const int qrow0 = qt * 128 + w * 32;

    // Q fragments for both 16-row groups (scale folded in at qkv)
    bf16x8 qa[2][4];
    #pragma unroll
    for (int h = 0; h < 2; ++h) {
        const __bf16* qb = Qg + (b * 4096 + qrow0 + h * 16 + ll) * 128 + lg * 8;
        #pragma unroll
        for (int kb = 0; kb < 4; ++kb) qa[h][kb] = *(const bf16x8*)(qb + kb * 32);
    }

    f32x4 o[2][8];
    #pragma unroll
    for (int h = 0; h < 2; ++h)
        #pragma unroll
        for (int dt = 0; dt < 8; ++dt) o[h][dt] = (f32x4){0.f, 0.f, 0.f, 0.f};
    float m[2] = {-1e30f, -1e30f}, lsum[2] = {0.f, 0.f};

    const __bf16* kbase = Kg + ((long)b * 4096 + s * kv_len) * 128;
    const __bf16* vbase = Vt + (long)b * 128 * 4096 + s * kv_len;

    // per-lane pre-swizzled source offsets; LDS dest stays linear
    int ksrc_off[4], vsrc_off[4];
    #pragma unroll
    for (int ii = 0; ii < 4; ++ii) {
        int u = w * 256 + ii * 64 + l;               // 16B unit index, [0,1024)
        int kr = u >> 4, kc = u & 15;
        ksrc_off[ii] = kr * 128 + ((kc ^ (kr & 7)) * 8);
        int vr = u >> 3, vc = u & 7;
        vsrc_off[ii] = vr * 4096 + ((vc ^ (vr & 7)) * 8);
    }

    #define STAGE(kv)                                                          \
    do {                                                                       \
        _Pragma("unroll")                                                      \
        for (int ii = 0; ii < 4; ++ii)                                         \
            GLOAD_LDS16(kbase + (long)(kv) * 128 + ksrc_off[ii],               \
                        (char*)&Kl[0][0] + (w * 256 + ii * 64) * 16);          \
        _Pragma("unroll")                                                      \
        for (int ii = 0; ii < 4; ++ii)                                         \
            GLOAD_LDS16(vbase + (kv) + vsrc_off[ii],                           \
                        (char*)&Vl[0][0] + (w * 256 + ii * 64) * 16);          \
    } while (0)

    STAGE(0);
    asm volatile("s_waitcnt vmcnt(0)" ::: "memory");
    __syncthreads();

    const int nit = kv_len >> 6;
    for (int it = 0; it < nit; ++it) {
        // QK^T swapped: f[h][nt][r] = S[key = nt*16+lg*4+r][qrow(h) = ll]
        f32x4 f[2][4];
        #pragma unroll
        for (int h = 0; h < 2; ++h)
            #pragma unroll
            for (int nt = 0; nt < 4; ++nt) f[h][nt] = (f32x4){0.f, 0.f, 0.f, 0.f};
        #pragma unroll
        for (int nt = 0; nt < 4; ++nt) {
            #pragma unroll
            for (int kb = 0; kb < 4; ++kb) {
                bf16x8 kf = *(const bf16x8*)&Kl[nt * 16 + ll][((kb * 4 + lg) ^ sK) * 8];
                f[0][nt] = __builtin_amdgcn_mfma_f32_16x16x32_bf16(kf, qa[0][kb], f[0][nt], 0, 0, 0);
                f[1][nt] = __builtin_amdgcn_mfma_f32_16x16x32_bf16(kf, qa[1][kb], f[1][nt], 0, 0, 0);
            }
        }

        // softmax per row-group (lane scalar state for q-row ll)
        float alpha[2];
        #pragma unroll
        for (int h = 0; h < 2; ++h) {
            float mx = f[h][0][0];
            #pragma unroll
            for (int nt = 0; nt < 4; ++nt)
                #pragma unroll
                for (int r = 0; r < 4; ++r) mx = fmaxf(mx, f[h][nt][r]);
            mx = fmaxf(mx, __shfl_xor(mx, 16, 64));
            mx = fmaxf(mx, __shfl_xor(mx, 32, 64));
            float mnew = fmaxf(m[h], mx);
            alpha[h] = __expf(m[h] - mnew);
            float rsum = 0.f;
            #pragma unroll
            for (int nt = 0; nt < 4; ++nt) {
                __bf16 pb[4];
                #pragma unroll
                for (int r = 0; r < 4; ++r) {
                    float e = __expf(f[h][nt][r] - mnew);
                    pb[r] = (__bf16)e;
                    rsum += (float)pb[r];   // sum bf16-rounded P: normalization cancels
                }
                uint2 u2;
                u2.x = bf16bits(pb[0]) | (bf16bits(pb[1]) << 16);
                u2.y = bf16bits(pb[2]) | (bf16bits(pb[3]) << 16);
                *(uint2*)&PlT[w][h][ll][((nt * 4 + lg) ^ (sK << 1)) * 4] = u2;
            }
            rsum += __shfl_xor(rsum, 16, 64);
            rsum += __shfl_xor(rsum, 32, 64);
            lsum[h] = lsum[h] * alpha[h] + rsum;
            m[h] = mnew;
        }
        asm volatile("s_waitcnt lgkmcnt(0)" ::: "memory");
        __builtin_amdgcn_sched_barrier(0);

        // rescale O (alpha for q-rows lg*4+r held at lanes lg*4+r)
        #pragma unroll
        for (int h = 0; h < 2; ++h) {
            float arow[4];
            #pragma unroll
            for (int r = 0; r < 4; ++r) arow[r] = __shfl(alpha[h], lg * 4 + r, 64);
            #pragma unroll
            for (int dt = 0; dt < 8; ++dt)
                #pragma unroll
                for (int r = 0; r < 4; ++r) o[h][dt][r] *= arow[r];
        }

        // PV: each V fragment feeds both row-groups
        #pragma unroll
        for (int kc = 0; kc < 2; ++kc) {
            bf16x8 pa0 = *(const bf16x8*)&PlT[w][0][ll][((kc * 4 + lg) ^ sK) * 8];
            bf16x8 pa1 = *(const bf16x8*)&PlT[w][1][ll][((kc * 4 + lg) ^ sK) * 8];
            #pragma unroll
            for (int dt = 0; dt < 8; ++dt) {
                bf16x8 vb = *(const bf16x8*)&Vl[dt * 16 + ll][((kc * 4 + lg) ^ sK) * 8];
                o[0][dt] = __builtin_amdgcn_mfma_f32_16x16x32_bf16(pa0, vb, o[0][dt], 0, 0, 0);
                o[1][dt] = __builtin_amdgcn_mfma_f32_16x16x32_bf16(pa1, vb, o[1][dt], 0, 0, 0);
            }
        }

        __syncthreads();                 // all waves done reading tile `it`
        if (it + 1 < nit) STAGE((it + 1) * 64);
        asm volatile("s_waitcnt vmcnt(0)" ::: "memory");
        __syncthreads();                 // staged tile visible
    }
    #undef STAGE

    // epilogue: unnormalized partial O + per-row (m, lsum)
    #pragma unroll
    for (int h = 0; h < 2; ++h) {
        long rowbase = (long)s * (NB * SEQ) + b * 4096 + qrow0 + h * 16;
        float* op = Op + rowbase * 128;
        #pragma unroll
        for (int r = 0; r < 4; ++r)
            #pragma unroll
            for (int dt = 0; dt < 8; ++dt)
                op[(lg * 4 + r) * 128 + dt * 16 + ll] = o[h][dt][r];
        if (lg == 0) {
            m_p[rowbase + ll] = m[h];
            l_p[rowbase + ll] = lsum[h];
        }
    }
}

// ---------------------------------------------------------------------------
// Kernel 3: merge split-K partials.  grid 256 x 256 thr; 64 rows/block.
// ---------------------------------------------------------------------------
__global__ __launch_bounds__(256) void attn_merge(
    const float* __restrict__ Op, const float* __restrict__ m_p,
    const float* __restrict__ l_p, float* __restrict__ out, int nsplit)
{
    const int t = threadIdx.x;
    const int base_row = blockIdx.x * 64;
    #pragma unroll 1
    for (int k = 0; k < 8; ++k) {
        int u = t + k * 256;                 // float4 unit within 64x128 tile
        int row = base_row + (u >> 5);
        int dq = u & 31;
        float M = -1e30f;
        for (int sp = 0; sp < nsplit; ++sp)
            M = fmaxf(M, m_p[(long)sp * (NB * SEQ) + row]);
        float L = 0.f;
        float4 acc = {0.f, 0.f, 0.f, 0.f};
        for (int sp = 0; sp < nsplit; ++sp) {
            long rb2 = (long)sp * (NB * SEQ) + row;
            float a = __expf(m_p[rb2] - M);
            L += l_p[rb2] * a;
            float4 vv = *(const float4*)(Op + rb2 * 128 + dq * 4);
            acc.x += vv.x * a; acc.y += vv.y * a; acc.z += vv.z * a; acc.w += vv.w * a;
        }
        float inv = 1.f / L;
        float4 r4 = {acc.x * inv, acc.y * inv, acc.z * inv, acc.w * inv};
        *(float4*)(out + (long)row * 128 + dq * 4) = r4;
    }
}

extern "C" void kernel_launch(void* const* d_in, const int* in_sizes, int n_in,
                              void* d_out, int out_size, void* d_ws, size_t ws_size,
                              hipStream_t stream) {
    (void)in_sizes; (void)n_in; (void)out_size;
    const float* x  = (const float*)d_in[0];
    const float* Wq = (const float*)d_in[1];
    const float* bq = (const float*)d_in[2];
    const float* Wk = (const float*)d_in[3];
    const float* bk = (const float*)d_in[4];
    const float* Wv = (const float*)d_in[5];
    const float* bv = (const float*)d_in[6];
    float* out = (float*)d_out;

    const size_t qkv_elems = (size_t)NB * SEQ * DIM;          // 2 MB elems
    char* p = (char*)d_ws;
    __bf16* Q  = (__bf16*)p;        p += qkv_elems * 2;       // 4 MB
    __bf16* K  = (__bf16*)p;        p += qkv_elems * 2;       // 4 MB
    __bf16* Vt = (__bf16*)p;        p += qkv_elems * 2;       // 4 MB
    __bf16* Wh = (__bf16*)p;        p += 3 * DIM * DIM * 2;   // 96 KB
    __bf16* Wl = (__bf16*)p;        p += 3 * DIM * DIM * 2;   // 96 KB
    size_t used = (size_t)(p - (char*)d_ws);

    // partials: per split 8 MB O + 64 KB m + 64 KB l
    const size_t per_split = (size_t)NB * SEQ * DIM * 4 + 2 * (size_t)NB * SEQ * 4;
    int nsplit = 4;
    while (nsplit > 1 && used + (size_t)nsplit * per_split > ws_size) nsplit >>= 1;

    float* Op  = (float*)p;                      p += (size_t)nsplit * NB * SEQ * DIM * 4;
    float* m_p = (float*)p;                      p += (size_t)nsplit * NB * SEQ * 4;
    float* l_p = (float*)p;

    wconv<<<48, 256, 0, stream>>>(Wq, Wk, Wv, Wh, Wl);
    dim3 g1(256, 3), b1(256);
    qkv_proj<<<g1, b1, 0, stream>>>(x, Wh, Wl, bq, bk, bv, Q, K, Vt);
    dim3 g2(128, nsplit);
    attn_fwd<<<g2, 256, 0, stream>>>(Q, K, Vt, Op, m_p, l_p, SEQ / nsplit);
    attn_merge<<<256, 256, 0, stream>>>(Op, m_p, l_p, out, nsplit);
}